// Round 8
// baseline (298.223 us; speedup 1.0000x reference)
//
#include <hip/hip_runtime.h>
#include <math.h>

static constexpr int NN = 100000;   // nodes
static constexpr int NE = 1600000;  // edges
static constexpr float BN_EPS = 1e-5f;
static constexpr int K_BKT = (NN + 255) / 256;   // 391 coarse buckets (dst>>8)
static constexpr int CH = 8192;                  // edges per partition block

typedef __attribute__((ext_vector_type(8))) short bf16x8;
typedef __attribute__((ext_vector_type(4))) float f32x4;

// bf16 helpers (RNE pack, exact unpack)
__device__ __forceinline__ unsigned short f2bf(float f) {
    unsigned int u = __float_as_uint(f);
    u += 0x7fffu + ((u >> 16) & 1u);
    return (unsigned short)(u >> 16);
}
__device__ __forceinline__ float bf2f(unsigned short b) {
    return __uint_as_float(((unsigned int)b) << 16);
}

// ---------------- utility ----------------
__global__ void zero_i32(int* __restrict__ p, int n) {
    int i = blockIdx.x * blockDim.x + threadIdx.x;
    if (i < n) p[i] = 0;
}

// ---------------- coarse bucket histogram (LDS pre-aggregated) ----------------
__global__ __launch_bounds__(256) void bucket_hist(
    const int* __restrict__ dst, int* __restrict__ bhist, int e)
{
    __shared__ int h[K_BKT];
    for (int i = threadIdx.x; i < K_BKT; i += 256) h[i] = 0;
    __syncthreads();
    int stride = gridDim.x * 256;
    for (int i = blockIdx.x * 256 + threadIdx.x; i < e; i += stride)
        atomicAdd(&h[((unsigned)dst[i]) >> 8], 1);
    __syncthreads();
    for (int i = threadIdx.x; i < K_BKT; i += 256)
        if (h[i]) atomicAdd(&bhist[i], h[i]);
}

// ---------------- scan 391 bucket counts -> bases & cursors (1 block) --------
__global__ __launch_bounds__(256) void scan_buckets(
    const int* __restrict__ bhist, int* __restrict__ bbase, int* __restrict__ bcur)
{
    __shared__ int a[512];
    int tid = threadIdx.x;
    a[tid]       = (tid < K_BKT) ? bhist[tid] : 0;
    a[tid + 256] = (tid + 256 < K_BKT) ? bhist[tid + 256] : 0;
    __syncthreads();
    for (int d = 1; d < 512; d <<= 1) {
        int x0 = (tid >= d) ? a[tid - d] : 0;
        int i1 = tid + 256;
        int x1 = (i1 >= d) ? a[i1 - d] : 0;
        __syncthreads();
        a[tid] += x0;
        a[i1]  += x1;
        __syncthreads();
    }
    if (tid < K_BKT) {
        int ex = (tid == 0) ? 0 : a[tid - 1];
        bbase[tid] = ex; bcur[tid] = ex;
    }
    int i1 = tid + 256;
    if (i1 < K_BKT) {
        int ex = a[i1 - 1];
        bbase[i1] = ex; bcur[i1] = ex;
    }
}

// ---------------- partition: bucket-grouped staged writes (coalesced runs) ---
__global__ __launch_bounds__(256) void partition_edges(
    const int* __restrict__ src, const int* __restrict__ dst,
    int* __restrict__ bcur, int* __restrict__ staged, int e)
{
    __shared__ int s_out[CH];       // 32 KB
    __shared__ int cntL[512];       // counts -> inclusive scan
    __shared__ int gbase[K_BKT];
    __shared__ int curL[K_BKT];

    int tid = threadIdx.x;
    int c0 = blockIdx.x * CH;
    int cend = min(c0 + CH, e);

    for (int i = tid; i < 512; i += 256) cntL[i] = 0;
    __syncthreads();

    for (int i = c0 + tid; i < cend; i += 256)
        atomicAdd(&cntL[((unsigned)dst[i]) >> 8], 1);
    __syncthreads();

    for (int b = tid; b < K_BKT; b += 256) {
        int c = cntL[b];
        gbase[b] = (c > 0) ? atomicAdd(&bcur[b], c) : 0;
    }
    __syncthreads();

    for (int d = 1; d < 512; d <<= 1) {
        int x0 = (tid >= d) ? cntL[tid - d] : 0;
        int i1 = tid + 256;
        int x1 = (i1 >= d) ? cntL[i1 - d] : 0;
        __syncthreads();
        cntL[tid] += x0;
        cntL[i1]  += x1;
        __syncthreads();
    }
    for (int b = tid; b < K_BKT; b += 256)
        curL[b] = (b == 0) ? 0 : cntL[b - 1];
    __syncthreads();

    for (int i = c0 + tid; i < cend; i += 256) {
        int s = src[i];
        int d = dst[i];
        int b = ((unsigned)d) >> 8;
        int r = atomicAdd(&curL[b], 1);
        s_out[r] = s | ((d & 255) << 24);
    }
    __syncthreads();

    int wave = tid >> 6, lane = tid & 63;
    for (int b = wave; b < K_BKT; b += 4) {
        int lo = (b == 0) ? 0 : cntL[b - 1];
        int hi = cntL[b];
        int gb = gbase[b];
        for (int i = lo + lane; i < hi; i += 64)
            staged[gb + (i - lo)] = s_out[i];
    }
}

// ---------------- place: per-bucket CSR finalize (XCD-local writes) ----------
__global__ __launch_bounds__(256) void place_edges(
    const int* __restrict__ bbase, const int* __restrict__ staged,
    int* __restrict__ esrc, int* __restrict__ off, int* __restrict__ cnt,
    float* __restrict__ dinv, int n, int e)
{
    __shared__ int cntL[256];
    __shared__ int scn[256];
    __shared__ int curL[256];
    int b = blockIdx.x;
    int tid = threadIdx.x;
    int node0 = b << 8;
    int nN = min(256, n - node0);
    int beg = bbase[b];
    int end = (b == (int)gridDim.x - 1) ? e : bbase[b + 1];

    cntL[tid] = 0;
    __syncthreads();
    for (int i = beg + tid; i < end; i += 256)
        atomicAdd(&cntL[((unsigned)staged[i]) >> 24], 1);
    __syncthreads();
    scn[tid] = cntL[tid];
    __syncthreads();
    for (int d = 1; d < 256; d <<= 1) {
        int x = (tid >= d) ? scn[tid - d] : 0;
        __syncthreads();
        scn[tid] += x;
        __syncthreads();
    }
    int lofs = (tid == 0) ? 0 : scn[tid - 1];
    if (tid < nN) {
        int node = node0 + tid;
        off[node] = beg + lofs;
        cnt[node] = cntL[tid];
        dinv[node] = rsqrtf((float)cntL[tid] + 1.0f);
    }
    curL[tid] = beg + lofs;
    __syncthreads();
    for (int i = beg + tid; i < end; i += 256) {
        int u = staged[i];
        int pos = atomicAdd(&curL[((unsigned)u) >> 24], 1);
        esrc[pos] = u & 0x00FFFFFF;
    }
}

// ---------------- W prep: fragment-ready blob ----------------
template<int K, int FOUT>
__global__ __launch_bounds__(256) void prep_w(
    const float* __restrict__ W, unsigned short* __restrict__ blob)
{
    constexpr int CT = FOUT / 16;
    constexpr int KS = (3 * K) / 32;
    int t = blockIdx.x * 256 + threadIdx.x;
    if (t >= KS * CT * 64) return;
    int lane = t & 63;
    int ct   = (t >> 6) % CT;
    int ks   = (t >> 6) / CT;
    int col  = ct * 16 + (lane & 15);
    int k0   = ks * 32 + (lane >> 4) * 8;

    union { bf16x8 v; unsigned short e[8]; } u;
#pragma unroll
    for (int j = 0; j < 8; ++j) {
        int kp = k0 + j;
        unsigned short r;
        if (kp < 2 * K) {
            int k = (kp < K) ? kp : kp - K;
            r = f2bf(W[k * FOUT + col]);
        } else {
            float f = W[(kp - 2 * K) * FOUT + col];
            unsigned short h = f2bf(f);
            r = f2bf(f - bf2f(h));
        }
        u.e[j] = r;
    }
    *reinterpret_cast<bf16x8*>(blob + (size_t)t * 8) = u.v;
}

// ---------------- MFMA GEMM: hw' = (h @ W) * dinv, stored bf16 ----------------
template<int K, int FOUT>
__global__ __launch_bounds__(256) void gemm_mfma(
    const float* __restrict__ h, const unsigned short* __restrict__ wtb,
    const float* __restrict__ dinv, unsigned short* __restrict__ hw, int n)
{
    constexpr int PAD = 8;
    constexpr int LDA = 2 * K + PAD;
    constexpr int CT  = FOUT / 16;
    constexpr int KS  = (3 * K) / 32;
    __shared__ unsigned short As[64 * LDA];

    const int tid  = threadIdx.x;
    const int row0 = blockIdx.x * 64;

    constexpr int QK = K / 4;
    for (int i = tid; i < 64 * QK; i += 256) {
        int r = i / QK;
        int q = i % QK;
        int g = row0 + r;
        float4 v;
        if (g < n) v = *reinterpret_cast<const float4*>(h + (size_t)g * K + q * 4);
        else       v = make_float4(0.f, 0.f, 0.f, 0.f);
        ushort4 hi, lo;
        hi.x = f2bf(v.x); lo.x = f2bf(v.x - bf2f(hi.x));
        hi.y = f2bf(v.y); lo.y = f2bf(v.y - bf2f(hi.y));
        hi.z = f2bf(v.z); lo.z = f2bf(v.z - bf2f(hi.z));
        hi.w = f2bf(v.w); lo.w = f2bf(v.w - bf2f(hi.w));
        *reinterpret_cast<ushort4*>(&As[r * LDA + q * 4])     = hi;
        *reinterpret_cast<ushort4*>(&As[r * LDA + K + q * 4]) = lo;
    }
    __syncthreads();

    const int wave = tid >> 6;
    const int lane = tid & 63;
    const int l15  = lane & 15;
    const int kgrp = (lane >> 4) * 8;
    const int arow = wave * 16 + l15;

    const unsigned short* wlane = wtb + lane * 8;   // + (ks*CT+ct)*512 immediates

    f32x4 acc[CT];
#pragma unroll
    for (int ct = 0; ct < CT; ++ct) acc[ct] = (f32x4){0.f, 0.f, 0.f, 0.f};

#pragma unroll
    for (int ks = 0; ks < KS; ++ks) {
        int kp = ks * 32 + kgrp;
        int ka = (kp >= 2 * K) ? kp - 2 * K : kp;
        bf16x8 a = *reinterpret_cast<const bf16x8*>(&As[arow * LDA + ka]);
#pragma unroll
        for (int ct = 0; ct < CT; ++ct) {
            bf16x8 b = *reinterpret_cast<const bf16x8*>(wlane + (ks * CT + ct) * 512);
            acc[ct] = __builtin_amdgcn_mfma_f32_16x16x32_bf16(a, b, acc[ct], 0, 0, 0);
        }
    }

    const int rbase = wave * 16 + (lane >> 4) * 4;
    float dv[4];
#pragma unroll
    for (int j = 0; j < 4; ++j) {
        int g = row0 + rbase + j;
        dv[j] = (g < n) ? dinv[g] : 0.f;
    }
#pragma unroll
    for (int ct = 0; ct < CT; ++ct) {
#pragma unroll
        for (int j = 0; j < 4; ++j) {
            int g = row0 + rbase + j;
            if (g < n) hw[(size_t)g * FOUT + ct * 16 + l15] = f2bf(acc[ct][j] * dv[j]);
        }
    }
}

// ---------------- gather + self-loop + bias + BN + ReLU (uint4 = 8 bf16/lane) -
// One node per WAVE. SG = F/8 lanes cover one row; NSG = 64/SG edges per iter.
template<int F>
__global__ __launch_bounds__(256) void gather_bn_relu(
    const int* __restrict__ off, const int* __restrict__ cnt,
    const int* __restrict__ esrc, const float* __restrict__ dinv,
    const unsigned short* __restrict__ hw, const float* __restrict__ bias,
    const float* __restrict__ g, const float* __restrict__ be,
    const float* __restrict__ m, const float* __restrict__ v,
    float* __restrict__ hout, int n)
{
    constexpr int SG  = F / 8;     // lanes covering one row
    constexpr int NSG = 64 / SG;   // edges per iteration
    int node = (blockIdx.x * 256 + threadIdx.x) >> 6;
    if (node >= n) return;
    int lane = threadIdx.x & 63;
    int sg = lane / SG;            // edge slot
    int p  = lane % SG;            // col octet: cols [8p, 8p+7]

    int beg = off[node];
    int num = cnt[node];

    float a0=0.f,a1=0.f,a2=0.f,a3=0.f,a4=0.f,a5=0.f,a6=0.f,a7=0.f;
#define ACCUM(w4)                                             \
    do {                                                      \
        a0 += __uint_as_float((w4).x << 16);                  \
        a1 += __uint_as_float((w4).x & 0xFFFF0000u);          \
        a2 += __uint_as_float((w4).y << 16);                  \
        a3 += __uint_as_float((w4).y & 0xFFFF0000u);          \
        a4 += __uint_as_float((w4).z << 16);                  \
        a5 += __uint_as_float((w4).z & 0xFFFF0000u);          \
        a6 += __uint_as_float((w4).w << 16);                  \
        a7 += __uint_as_float((w4).w & 0xFFFF0000u);          \
    } while (0)

    int j = sg;
    for (; j + NSG < num; j += 2 * NSG) {
        int s0 = esrc[beg + j];
        int s1 = esrc[beg + j + NSG];
        uint4 wa = *reinterpret_cast<const uint4*>(hw + (size_t)s0 * F + 8 * p);
        uint4 wb = *reinterpret_cast<const uint4*>(hw + (size_t)s1 * F + 8 * p);
        ACCUM(wa);
        ACCUM(wb);
    }
    if (j < num) {
        int s0 = esrc[beg + j];
        uint4 wa = *reinterpret_cast<const uint4*>(hw + (size_t)s0 * F + 8 * p);
        ACCUM(wa);
    }
    if (sg == 0) {   // self-loop (hw' = hw*dinv)
        uint4 wa = *reinterpret_cast<const uint4*>(hw + (size_t)node * F + 8 * p);
        ACCUM(wa);
    }
#undef ACCUM

#pragma unroll
    for (int d = SG; d < 64; d <<= 1) {
        a0 += __shfl_xor(a0, d);
        a1 += __shfl_xor(a1, d);
        a2 += __shfl_xor(a2, d);
        a3 += __shfl_xor(a3, d);
        a4 += __shfl_xor(a4, d);
        a5 += __shfl_xor(a5, d);
        a6 += __shfl_xor(a6, d);
        a7 += __shfl_xor(a7, d);
    }

    if (sg == 0) {
        int c0 = 8 * p;
        float dn = dinv[node];
        float4 g0 = *reinterpret_cast<const float4*>(g + c0);
        float4 g1 = *reinterpret_cast<const float4*>(g + c0 + 4);
        float4 v0 = *reinterpret_cast<const float4*>(v + c0);
        float4 v1 = *reinterpret_cast<const float4*>(v + c0 + 4);
        float4 b0 = *reinterpret_cast<const float4*>(bias + c0);
        float4 b1 = *reinterpret_cast<const float4*>(bias + c0 + 4);
        float4 m0 = *reinterpret_cast<const float4*>(m + c0);
        float4 m1 = *reinterpret_cast<const float4*>(m + c0 + 4);
        float4 e0 = *reinterpret_cast<const float4*>(be + c0);
        float4 e1 = *reinterpret_cast<const float4*>(be + c0 + 4);
        float4 y0, y1;
        y0.x = fmaxf(g0.x * rsqrtf(v0.x + BN_EPS) * (dn * a0 + b0.x - m0.x) + e0.x, 0.f);
        y0.y = fmaxf(g0.y * rsqrtf(v0.y + BN_EPS) * (dn * a1 + b0.y - m0.y) + e0.y, 0.f);
        y0.z = fmaxf(g0.z * rsqrtf(v0.z + BN_EPS) * (dn * a2 + b0.z - m0.z) + e0.z, 0.f);
        y0.w = fmaxf(g0.w * rsqrtf(v0.w + BN_EPS) * (dn * a3 + b0.w - m0.w) + e0.w, 0.f);
        y1.x = fmaxf(g1.x * rsqrtf(v1.x + BN_EPS) * (dn * a4 + b1.x - m1.x) + e1.x, 0.f);
        y1.y = fmaxf(g1.y * rsqrtf(v1.y + BN_EPS) * (dn * a5 + b1.y - m1.y) + e1.y, 0.f);
        y1.z = fmaxf(g1.z * rsqrtf(v1.z + BN_EPS) * (dn * a6 + b1.z - m1.z) + e1.z, 0.f);
        y1.w = fmaxf(g1.w * rsqrtf(v1.w + BN_EPS) * (dn * a7 + b1.w - m1.w) + e1.w, 0.f);
        *reinterpret_cast<float4*>(hout + (size_t)node * F + c0)     = y0;
        *reinterpret_cast<float4*>(hout + (size_t)node * F + c0 + 4) = y1;
    }
}

// ---------------- final FC(16->8) + sigmoid ----------------
__global__ __launch_bounds__(256) void fc_sigmoid(
    const float* __restrict__ h, const float* __restrict__ W,
    const float* __restrict__ b, float* __restrict__ out, int n)
{
    __shared__ float Ws[16 * 8];
    __shared__ float bs[8];
    int tid = threadIdx.x;
    if (tid < 128) Ws[tid] = W[tid];
    if (tid < 8)   bs[tid] = b[tid];
    __syncthreads();

    int node = blockIdx.x * 256 + tid;
    if (node >= n) return;

    float hr[16];
    const float4* hp = reinterpret_cast<const float4*>(h + (size_t)node * 16);
#pragma unroll
    for (int q = 0; q < 4; ++q) {
        float4 t4 = hp[q];
        hr[q*4+0] = t4.x; hr[q*4+1] = t4.y; hr[q*4+2] = t4.z; hr[q*4+3] = t4.w;
    }
    float o[8];
#pragma unroll
    for (int c = 0; c < 8; ++c) o[c] = bs[c];
#pragma unroll
    for (int k = 0; k < 16; ++k) {
#pragma unroll
        for (int c = 0; c < 8; ++c) o[c] += hr[k] * Ws[k * 8 + c];
    }
    float4 o0, o1;
    o0.x = 1.0f / (1.0f + expf(-o[0]));
    o0.y = 1.0f / (1.0f + expf(-o[1]));
    o0.z = 1.0f / (1.0f + expf(-o[2]));
    o0.w = 1.0f / (1.0f + expf(-o[3]));
    o1.x = 1.0f / (1.0f + expf(-o[4]));
    o1.y = 1.0f / (1.0f + expf(-o[5]));
    o1.z = 1.0f / (1.0f + expf(-o[6]));
    o1.w = 1.0f / (1.0f + expf(-o[7]));
    float4* op = reinterpret_cast<float4*>(out + (size_t)node * 8);
    op[0] = o0;
    op[1] = o1;
}

// ---------------- launch ----------------
extern "C" void kernel_launch(void* const* d_in, const int* in_sizes, int n_in,
                              void* d_out, int out_size, void* d_ws, size_t ws_size,
                              hipStream_t stream) {
    const float* x   = (const float*)d_in[0];
    const int*   ei  = (const int*)  d_in[1];   // [2, E]: src row then dst row
    const float* W1  = (const float*)d_in[2];
    const float* b1  = (const float*)d_in[3];
    const float* g1  = (const float*)d_in[4];
    const float* be1 = (const float*)d_in[5];
    const float* m1  = (const float*)d_in[6];
    const float* v1  = (const float*)d_in[7];
    const float* W2  = (const float*)d_in[8];
    const float* b2  = (const float*)d_in[9];
    const float* g2  = (const float*)d_in[10];
    const float* be2 = (const float*)d_in[11];
    const float* m2  = (const float*)d_in[12];
    const float* v2  = (const float*)d_in[13];
    const float* W3  = (const float*)d_in[14];
    const float* b3  = (const float*)d_in[15];
    const float* g3  = (const float*)d_in[16];
    const float* be3 = (const float*)d_in[17];
    const float* m3  = (const float*)d_in[18];
    const float* v3  = (const float*)d_in[19];
    const float* fcW = (const float*)d_in[20];
    const float* fcb = (const float*)d_in[21];
    float* out = (float*)d_out;

    const int* src = ei;
    const int* dst = ei + NE;

    char* w = (char*)d_ws;
    float* dinv  = (float*)(w + 0);                 // N f32
    int*   cnt   = (int*)  (w + (512 << 10));       // N i32
    int*   off   = (int*)  (w + (1024 << 10));      // N i32
    int*   bhist = (int*)  (w + (1536 << 10));      // K_BKT i32
    int*   bbase = (int*)  (w + (1600 << 10));      // K_BKT i32
    int*   bcur  = (int*)  (w + (1664 << 10));      // K_BKT i32
    int*   staged= (int*)  (w + (2u << 20));        // E i32 = 6.4 MB
    unsigned short* wt1 = (unsigned short*)(w + (8600u << 10)); // 48 KB blob
    unsigned short* wt2 = wt1 + 24576;                           // 12 KB blob
    unsigned short* wt3 = wt2 + 6144;                            // 3 KB blob
    int*   esrc  = (int*)  (w + (9u << 20));        // E i32 = 6.4 MB
    unsigned short* hw = (unsigned short*)(w + (16u << 20)); // N*64 bf16
    float* H     = (float*)(w + (29u << 20));       // N*64 f32

    float* h1 = H;
    float* h2 = H;
    float* h3 = H;

    // ---- W prep (fragment-ready blobs) ----
    prep_w<128, 64><<<(12 * 4 * 64 + 255) / 256, 256, 0, stream>>>(W1, wt1);
    prep_w<64, 32><<<(6 * 2 * 64 + 255) / 256, 256, 0, stream>>>(W2, wt2);
    prep_w<32, 16><<<(3 * 1 * 64 + 255) / 256, 256, 0, stream>>>(W3, wt3);

    // ---- CSR build ----
    zero_i32<<<2, 256, 0, stream>>>(bhist, K_BKT);
    bucket_hist<<<256, 256, 0, stream>>>(dst, bhist, NE);
    scan_buckets<<<1, 256, 0, stream>>>(bhist, bbase, bcur);
    partition_edges<<<(NE + CH - 1) / CH, 256, 0, stream>>>(src, dst, bcur, staged, NE);
    place_edges<<<K_BKT, 256, 0, stream>>>(bbase, staged, esrc, off, cnt, dinv, NN, NE);

    const int GG = (NN * 64 + 255) / 256;   // one wave per node

    // layer 1: 128 -> 64
    gemm_mfma<128, 64><<<(NN + 63) / 64, 256, 0, stream>>>(x, wt1, dinv, hw, NN);
    gather_bn_relu<64><<<GG, 256, 0, stream>>>(
        off, cnt, esrc, dinv, hw, b1, g1, be1, m1, v1, h1, NN);

    // layer 2: 64 -> 32
    gemm_mfma<64, 32><<<(NN + 63) / 64, 256, 0, stream>>>(h1, wt2, dinv, hw, NN);
    gather_bn_relu<32><<<GG, 256, 0, stream>>>(
        off, cnt, esrc, dinv, hw, b2, g2, be2, m2, v2, h2, NN);

    // layer 3: 32 -> 16
    gemm_mfma<32, 16><<<(NN + 63) / 64, 256, 0, stream>>>(h2, wt3, dinv, hw, NN);
    gather_bn_relu<16><<<GG, 256, 0, stream>>>(
        off, cnt, esrc, dinv, hw, b3, g3, be3, m3, v3, h3, NN);

    // FC + sigmoid
    fc_sigmoid<<<(NN + 255) / 256, 256, 0, stream>>>(h3, fcW, fcb, out, NN);
}

// Round 9
// 276.182 us; speedup vs baseline: 1.0798x; 1.0798x over previous
//
#include <hip/hip_runtime.h>
#include <math.h>

static constexpr int NN = 100000;   // nodes
static constexpr int NE = 1600000;  // edges
static constexpr float BN_EPS = 1e-5f;
static constexpr int K_BKT = (NN + 255) / 256;   // 391 coarse buckets (dst>>8)
static constexpr int CH = 8192;                  // edges per partition block

typedef __attribute__((ext_vector_type(8))) short bf16x8;
typedef __attribute__((ext_vector_type(4))) float f32x4;

// bf16 helpers (RNE pack, exact unpack)
__device__ __forceinline__ unsigned short f2bf(float f) {
    unsigned int u = __float_as_uint(f);
    u += 0x7fffu + ((u >> 16) & 1u);
    return (unsigned short)(u >> 16);
}
__device__ __forceinline__ float bf2f(unsigned short b) {
    return __uint_as_float(((unsigned int)b) << 16);
}

// ---------------- utility ----------------
__global__ void zero_i32(int* __restrict__ p, int n) {
    int i = blockIdx.x * blockDim.x + threadIdx.x;
    if (i < n) p[i] = 0;
}

// ---------------- coarse bucket histogram (LDS pre-aggregated) ----------------
__global__ __launch_bounds__(256) void bucket_hist(
    const int* __restrict__ dst, int* __restrict__ bhist, int e)
{
    __shared__ int h[K_BKT];
    for (int i = threadIdx.x; i < K_BKT; i += 256) h[i] = 0;
    __syncthreads();
    int stride = gridDim.x * 256;
    for (int i = blockIdx.x * 256 + threadIdx.x; i < e; i += stride)
        atomicAdd(&h[((unsigned)dst[i]) >> 8], 1);
    __syncthreads();
    for (int i = threadIdx.x; i < K_BKT; i += 256)
        if (h[i]) atomicAdd(&bhist[i], h[i]);
}

// ---------------- scan 391 bucket counts -> bases & cursors (1 block) --------
__global__ __launch_bounds__(256) void scan_buckets(
    const int* __restrict__ bhist, int* __restrict__ bbase, int* __restrict__ bcur)
{
    __shared__ int a[512];
    int tid = threadIdx.x;
    a[tid]       = (tid < K_BKT) ? bhist[tid] : 0;
    a[tid + 256] = (tid + 256 < K_BKT) ? bhist[tid + 256] : 0;
    __syncthreads();
    for (int d = 1; d < 512; d <<= 1) {
        int x0 = (tid >= d) ? a[tid - d] : 0;
        int i1 = tid + 256;
        int x1 = (i1 >= d) ? a[i1 - d] : 0;
        __syncthreads();
        a[tid] += x0;
        a[i1]  += x1;
        __syncthreads();
    }
    if (tid < K_BKT) {
        int ex = (tid == 0) ? 0 : a[tid - 1];
        bbase[tid] = ex; bcur[tid] = ex;
    }
    int i1 = tid + 256;
    if (i1 < K_BKT) {
        int ex = a[i1 - 1];
        bbase[i1] = ex; bcur[i1] = ex;
    }
}

// ---------------- partition: bucket-grouped staged writes (coalesced runs) ---
__global__ __launch_bounds__(256) void partition_edges(
    const int* __restrict__ src, const int* __restrict__ dst,
    int* __restrict__ bcur, int* __restrict__ staged, int e)
{
    __shared__ int s_out[CH];       // 32 KB
    __shared__ int cntL[512];       // counts -> inclusive scan
    __shared__ int gbase[K_BKT];
    __shared__ int curL[K_BKT];

    int tid = threadIdx.x;
    int c0 = blockIdx.x * CH;
    int cend = min(c0 + CH, e);

    for (int i = tid; i < 512; i += 256) cntL[i] = 0;
    __syncthreads();

    for (int i = c0 + tid; i < cend; i += 256)
        atomicAdd(&cntL[((unsigned)dst[i]) >> 8], 1);
    __syncthreads();

    for (int b = tid; b < K_BKT; b += 256) {
        int c = cntL[b];
        gbase[b] = (c > 0) ? atomicAdd(&bcur[b], c) : 0;
    }
    __syncthreads();

    for (int d = 1; d < 512; d <<= 1) {
        int x0 = (tid >= d) ? cntL[tid - d] : 0;
        int i1 = tid + 256;
        int x1 = (i1 >= d) ? cntL[i1 - d] : 0;
        __syncthreads();
        cntL[tid] += x0;
        cntL[i1]  += x1;
        __syncthreads();
    }
    for (int b = tid; b < K_BKT; b += 256)
        curL[b] = (b == 0) ? 0 : cntL[b - 1];
    __syncthreads();

    for (int i = c0 + tid; i < cend; i += 256) {
        int s = src[i];
        int d = dst[i];
        int b = ((unsigned)d) >> 8;
        int r = atomicAdd(&curL[b], 1);
        s_out[r] = s | ((d & 255) << 24);
    }
    __syncthreads();

    int wave = tid >> 6, lane = tid & 63;
    for (int b = wave; b < K_BKT; b += 4) {
        int lo = (b == 0) ? 0 : cntL[b - 1];
        int hi = cntL[b];
        int gb = gbase[b];
        for (int i = lo + lane; i < hi; i += 64)
            staged[gb + (i - lo)] = s_out[i];
    }
}

// ---------------- place: per-bucket CSR finalize (XCD-local writes) ----------
__global__ __launch_bounds__(256) void place_edges(
    const int* __restrict__ bbase, const int* __restrict__ staged,
    int* __restrict__ esrc, int* __restrict__ off, int* __restrict__ cnt,
    float* __restrict__ dinv, int n, int e)
{
    __shared__ int cntL[256];
    __shared__ int scn[256];
    __shared__ int curL[256];
    int b = blockIdx.x;
    int tid = threadIdx.x;
    int node0 = b << 8;
    int nN = min(256, n - node0);
    int beg = bbase[b];
    int end = (b == (int)gridDim.x - 1) ? e : bbase[b + 1];

    cntL[tid] = 0;
    __syncthreads();
    for (int i = beg + tid; i < end; i += 256)
        atomicAdd(&cntL[((unsigned)staged[i]) >> 24], 1);
    __syncthreads();
    scn[tid] = cntL[tid];
    __syncthreads();
    for (int d = 1; d < 256; d <<= 1) {
        int x = (tid >= d) ? scn[tid - d] : 0;
        __syncthreads();
        scn[tid] += x;
        __syncthreads();
    }
    int lofs = (tid == 0) ? 0 : scn[tid - 1];
    if (tid < nN) {
        int node = node0 + tid;
        off[node] = beg + lofs;
        cnt[node] = cntL[tid];
        dinv[node] = rsqrtf((float)cntL[tid] + 1.0f);
    }
    curL[tid] = beg + lofs;
    __syncthreads();
    for (int i = beg + tid; i < end; i += 256) {
        int u = staged[i];
        int pos = atomicAdd(&curL[((unsigned)u) >> 24], 1);
        esrc[pos] = u & 0x00FFFFFF;
    }
}

// ---------------- W prep: fragment-ready blob ----------------
template<int K, int FOUT>
__global__ __launch_bounds__(256) void prep_w(
    const float* __restrict__ W, unsigned short* __restrict__ blob)
{
    constexpr int CT = FOUT / 16;
    constexpr int KS = (3 * K) / 32;
    int t = blockIdx.x * 256 + threadIdx.x;
    if (t >= KS * CT * 64) return;
    int lane = t & 63;
    int ct   = (t >> 6) % CT;
    int ks   = (t >> 6) / CT;
    int col  = ct * 16 + (lane & 15);
    int k0   = ks * 32 + (lane >> 4) * 8;

    union { bf16x8 v; unsigned short e[8]; } u;
#pragma unroll
    for (int j = 0; j < 8; ++j) {
        int kp = k0 + j;
        unsigned short r;
        if (kp < 2 * K) {
            int k = (kp < K) ? kp : kp - K;
            r = f2bf(W[k * FOUT + col]);
        } else {
            float f = W[(kp - 2 * K) * FOUT + col];
            unsigned short h = f2bf(f);
            r = f2bf(f - bf2f(h));
        }
        u.e[j] = r;
    }
    *reinterpret_cast<bf16x8*>(blob + (size_t)t * 8) = u.v;
}

// ---------------- MFMA GEMM: hw' = (h @ W) * dinv, stored bf16 ----------------
template<int K, int FOUT>
__global__ __launch_bounds__(256) void gemm_mfma(
    const float* __restrict__ h, const unsigned short* __restrict__ wtb,
    const float* __restrict__ dinv, unsigned short* __restrict__ hw, int n)
{
    constexpr int PAD = 8;
    constexpr int LDA = 2 * K + PAD;
    constexpr int CT  = FOUT / 16;
    constexpr int KS  = (3 * K) / 32;
    __shared__ unsigned short As[64 * LDA];

    const int tid  = threadIdx.x;
    const int row0 = blockIdx.x * 64;

    constexpr int QK = K / 4;
    for (int i = tid; i < 64 * QK; i += 256) {
        int r = i / QK;
        int q = i % QK;
        int g = row0 + r;
        float4 v;
        if (g < n) v = *reinterpret_cast<const float4*>(h + (size_t)g * K + q * 4);
        else       v = make_float4(0.f, 0.f, 0.f, 0.f);
        ushort4 hi, lo;
        hi.x = f2bf(v.x); lo.x = f2bf(v.x - bf2f(hi.x));
        hi.y = f2bf(v.y); lo.y = f2bf(v.y - bf2f(hi.y));
        hi.z = f2bf(v.z); lo.z = f2bf(v.z - bf2f(hi.z));
        hi.w = f2bf(v.w); lo.w = f2bf(v.w - bf2f(hi.w));
        *reinterpret_cast<ushort4*>(&As[r * LDA + q * 4])     = hi;
        *reinterpret_cast<ushort4*>(&As[r * LDA + K + q * 4]) = lo;
    }
    __syncthreads();

    const int wave = tid >> 6;
    const int lane = tid & 63;
    const int l15  = lane & 15;
    const int kgrp = (lane >> 4) * 8;
    const int arow = wave * 16 + l15;

    const unsigned short* wlane = wtb + lane * 8;   // + (ks*CT+ct)*512 immediates

    f32x4 acc[CT];
#pragma unroll
    for (int ct = 0; ct < CT; ++ct) acc[ct] = (f32x4){0.f, 0.f, 0.f, 0.f};

#pragma unroll
    for (int ks = 0; ks < KS; ++ks) {
        int kp = ks * 32 + kgrp;
        int ka = (kp >= 2 * K) ? kp - 2 * K : kp;
        bf16x8 a = *reinterpret_cast<const bf16x8*>(&As[arow * LDA + ka]);
#pragma unroll
        for (int ct = 0; ct < CT; ++ct) {
            bf16x8 b = *reinterpret_cast<const bf16x8*>(wlane + (ks * CT + ct) * 512);
            acc[ct] = __builtin_amdgcn_mfma_f32_16x16x32_bf16(a, b, acc[ct], 0, 0, 0);
        }
    }

    const int rbase = wave * 16 + (lane >> 4) * 4;
    float dv[4];
#pragma unroll
    for (int j = 0; j < 4; ++j) {
        int g = row0 + rbase + j;
        dv[j] = (g < n) ? dinv[g] : 0.f;
    }
#pragma unroll
    for (int ct = 0; ct < CT; ++ct) {
#pragma unroll
        for (int j = 0; j < 4; ++j) {
            int g = row0 + rbase + j;
            if (g < n) hw[(size_t)g * FOUT + ct * 16 + l15] = f2bf(acc[ct][j] * dv[j]);
        }
    }
}

// ---------------- gather + self-loop + bias + BN + ReLU (ushort4, unroll 4) --
// One node per WAVE. SG = F/4 lanes cover one row; NSG = 64/SG edges per round;
// 4 rounds in flight per main-loop iteration (4 independent row loads).
template<int F>
__global__ __launch_bounds__(256) void gather_bn_relu(
    const int* __restrict__ off, const int* __restrict__ cnt,
    const int* __restrict__ esrc, const float* __restrict__ dinv,
    const unsigned short* __restrict__ hw, const float* __restrict__ bias,
    const float* __restrict__ g, const float* __restrict__ be,
    const float* __restrict__ m, const float* __restrict__ v,
    float* __restrict__ hout, int n)
{
    constexpr int SG  = F / 4;     // lanes covering one row
    constexpr int NSG = 64 / SG;   // edges per round
    int node = (blockIdx.x * 256 + threadIdx.x) >> 6;
    if (node >= n) return;
    int lane = threadIdx.x & 63;
    int sg = lane / SG;            // edge slot
    int p  = lane % SG;            // col quad: cols [4p, 4p+3]

    int beg = off[node];
    int num = cnt[node];

    float sx = 0.f, sy = 0.f, sz = 0.f, sw = 0.f;
    int j = sg;
    for (; j + 3 * NSG < num; j += 4 * NSG) {
        int s0 = esrc[beg + j];
        int s1 = esrc[beg + j + NSG];
        int s2 = esrc[beg + j + 2 * NSG];
        int s3 = esrc[beg + j + 3 * NSG];
        ushort4 a = *reinterpret_cast<const ushort4*>(hw + (size_t)s0 * F + 4 * p);
        ushort4 b = *reinterpret_cast<const ushort4*>(hw + (size_t)s1 * F + 4 * p);
        ushort4 c = *reinterpret_cast<const ushort4*>(hw + (size_t)s2 * F + 4 * p);
        ushort4 d = *reinterpret_cast<const ushort4*>(hw + (size_t)s3 * F + 4 * p);
        sx += (bf2f(a.x) + bf2f(b.x)) + (bf2f(c.x) + bf2f(d.x));
        sy += (bf2f(a.y) + bf2f(b.y)) + (bf2f(c.y) + bf2f(d.y));
        sz += (bf2f(a.z) + bf2f(b.z)) + (bf2f(c.z) + bf2f(d.z));
        sw += (bf2f(a.w) + bf2f(b.w)) + (bf2f(c.w) + bf2f(d.w));
    }
    for (; j < num; j += NSG) {
        int s0 = esrc[beg + j];
        ushort4 a = *reinterpret_cast<const ushort4*>(hw + (size_t)s0 * F + 4 * p);
        sx += bf2f(a.x); sy += bf2f(a.y); sz += bf2f(a.z); sw += bf2f(a.w);
    }
    if (sg == 0) {   // self-loop (hw' = hw*dinv)
        ushort4 a = *reinterpret_cast<const ushort4*>(hw + (size_t)node * F + 4 * p);
        sx += bf2f(a.x); sy += bf2f(a.y); sz += bf2f(a.z); sw += bf2f(a.w);
    }

#pragma unroll
    for (int d = SG; d < 64; d <<= 1) {
        sx += __shfl_xor(sx, d);
        sy += __shfl_xor(sy, d);
        sz += __shfl_xor(sz, d);
        sw += __shfl_xor(sw, d);
    }

    if (sg == 0) {
        int c0 = 4 * p;
        float4 gg = *reinterpret_cast<const float4*>(g + c0);
        float4 vv = *reinterpret_cast<const float4*>(v + c0);
        float4 bb = *reinterpret_cast<const float4*>(bias + c0);
        float4 mm = *reinterpret_cast<const float4*>(m + c0);
        float4 ee = *reinterpret_cast<const float4*>(be + c0);
        float dn = dinv[node];
        float4 y;
        y.x = fmaxf(gg.x * rsqrtf(vv.x + BN_EPS) * (dn * sx + bb.x - mm.x) + ee.x, 0.f);
        y.y = fmaxf(gg.y * rsqrtf(vv.y + BN_EPS) * (dn * sy + bb.y - mm.y) + ee.y, 0.f);
        y.z = fmaxf(gg.z * rsqrtf(vv.z + BN_EPS) * (dn * sz + bb.z - mm.z) + ee.z, 0.f);
        y.w = fmaxf(gg.w * rsqrtf(vv.w + BN_EPS) * (dn * sw + bb.w - mm.w) + ee.w, 0.f);
        *reinterpret_cast<float4*>(hout + (size_t)node * F + c0) = y;
    }
}

// ---------------- final FC(16->8) + sigmoid ----------------
__global__ __launch_bounds__(256) void fc_sigmoid(
    const float* __restrict__ h, const float* __restrict__ W,
    const float* __restrict__ b, float* __restrict__ out, int n)
{
    __shared__ float Ws[16 * 8];
    __shared__ float bs[8];
    int tid = threadIdx.x;
    if (tid < 128) Ws[tid] = W[tid];
    if (tid < 8)   bs[tid] = b[tid];
    __syncthreads();

    int node = blockIdx.x * 256 + tid;
    if (node >= n) return;

    float hr[16];
    const float4* hp = reinterpret_cast<const float4*>(h + (size_t)node * 16);
#pragma unroll
    for (int q = 0; q < 4; ++q) {
        float4 t4 = hp[q];
        hr[q*4+0] = t4.x; hr[q*4+1] = t4.y; hr[q*4+2] = t4.z; hr[q*4+3] = t4.w;
    }
    float o[8];
#pragma unroll
    for (int c = 0; c < 8; ++c) o[c] = bs[c];
#pragma unroll
    for (int k = 0; k < 16; ++k) {
#pragma unroll
        for (int c = 0; c < 8; ++c) o[c] += hr[k] * Ws[k * 8 + c];
    }
    float4 o0, o1;
    o0.x = 1.0f / (1.0f + expf(-o[0]));
    o0.y = 1.0f / (1.0f + expf(-o[1]));
    o0.z = 1.0f / (1.0f + expf(-o[2]));
    o0.w = 1.0f / (1.0f + expf(-o[3]));
    o1.x = 1.0f / (1.0f + expf(-o[4]));
    o1.y = 1.0f / (1.0f + expf(-o[5]));
    o1.z = 1.0f / (1.0f + expf(-o[6]));
    o1.w = 1.0f / (1.0f + expf(-o[7]));
    float4* op = reinterpret_cast<float4*>(out + (size_t)node * 8);
    op[0] = o0;
    op[1] = o1;
}

// ---------------- launch ----------------
extern "C" void kernel_launch(void* const* d_in, const int* in_sizes, int n_in,
                              void* d_out, int out_size, void* d_ws, size_t ws_size,
                              hipStream_t stream) {
    const float* x   = (const float*)d_in[0];
    const int*   ei  = (const int*)  d_in[1];   // [2, E]: src row then dst row
    const float* W1  = (const float*)d_in[2];
    const float* b1  = (const float*)d_in[3];
    const float* g1  = (const float*)d_in[4];
    const float* be1 = (const float*)d_in[5];
    const float* m1  = (const float*)d_in[6];
    const float* v1  = (const float*)d_in[7];
    const float* W2  = (const float*)d_in[8];
    const float* b2  = (const float*)d_in[9];
    const float* g2  = (const float*)d_in[10];
    const float* be2 = (const float*)d_in[11];
    const float* m2  = (const float*)d_in[12];
    const float* v2  = (const float*)d_in[13];
    const float* W3  = (const float*)d_in[14];
    const float* b3  = (const float*)d_in[15];
    const float* g3  = (const float*)d_in[16];
    const float* be3 = (const float*)d_in[17];
    const float* m3  = (const float*)d_in[18];
    const float* v3  = (const float*)d_in[19];
    const float* fcW = (const float*)d_in[20];
    const float* fcb = (const float*)d_in[21];
    float* out = (float*)d_out;

    const int* src = ei;
    const int* dst = ei + NE;

    char* w = (char*)d_ws;
    float* dinv  = (float*)(w + 0);                 // N f32
    int*   cnt   = (int*)  (w + (512 << 10));       // N i32
    int*   off   = (int*)  (w + (1024 << 10));      // N i32
    int*   bhist = (int*)  (w + (1536 << 10));      // K_BKT i32
    int*   bbase = (int*)  (w + (1600 << 10));      // K_BKT i32
    int*   bcur  = (int*)  (w + (1664 << 10));      // K_BKT i32
    int*   staged= (int*)  (w + (2u << 20));        // E i32 = 6.4 MB
    unsigned short* wt1 = (unsigned short*)(w + (8600u << 10)); // 48 KB blob
    unsigned short* wt2 = wt1 + 24576;                           // 12 KB blob
    unsigned short* wt3 = wt2 + 6144;                            // 3 KB blob
    int*   esrc  = (int*)  (w + (9u << 20));        // E i32 = 6.4 MB
    unsigned short* hw = (unsigned short*)(w + (16u << 20)); // N*64 bf16
    float* H     = (float*)(w + (29u << 20));       // N*64 f32

    float* h1 = H;
    float* h2 = H;
    float* h3 = H;

    // ---- W prep (fragment-ready blobs) ----
    prep_w<128, 64><<<(12 * 4 * 64 + 255) / 256, 256, 0, stream>>>(W1, wt1);
    prep_w<64, 32><<<(6 * 2 * 64 + 255) / 256, 256, 0, stream>>>(W2, wt2);
    prep_w<32, 16><<<(3 * 1 * 64 + 255) / 256, 256, 0, stream>>>(W3, wt3);

    // ---- CSR build ----
    zero_i32<<<2, 256, 0, stream>>>(bhist, K_BKT);
    bucket_hist<<<256, 256, 0, stream>>>(dst, bhist, NE);
    scan_buckets<<<1, 256, 0, stream>>>(bhist, bbase, bcur);
    partition_edges<<<(NE + CH - 1) / CH, 256, 0, stream>>>(src, dst, bcur, staged, NE);
    place_edges<<<K_BKT, 256, 0, stream>>>(bbase, staged, esrc, off, cnt, dinv, NN, NE);

    const int GG = (NN * 64 + 255) / 256;   // one wave per node

    // layer 1: 128 -> 64
    gemm_mfma<128, 64><<<(NN + 63) / 64, 256, 0, stream>>>(x, wt1, dinv, hw, NN);
    gather_bn_relu<64><<<GG, 256, 0, stream>>>(
        off, cnt, esrc, dinv, hw, b1, g1, be1, m1, v1, h1, NN);

    // layer 2: 64 -> 32
    gemm_mfma<64, 32><<<(NN + 63) / 64, 256, 0, stream>>>(h1, wt2, dinv, hw, NN);
    gather_bn_relu<32><<<GG, 256, 0, stream>>>(
        off, cnt, esrc, dinv, hw, b2, g2, be2, m2, v2, h2, NN);

    // layer 3: 32 -> 16
    gemm_mfma<32, 16><<<(NN + 63) / 64, 256, 0, stream>>>(h2, wt3, dinv, hw, NN);
    gather_bn_relu<16><<<GG, 256, 0, stream>>>(
        off, cnt, esrc, dinv, hw, b3, g3, be3, m3, v3, h3, NN);

    // FC + sigmoid
    fc_sigmoid<<<(NN + 255) / 256, 256, 0, stream>>>(h3, fcW, fcb, out, NN);
}

// Round 10
// 267.916 us; speedup vs baseline: 1.1131x; 1.0309x over previous
//
#include <hip/hip_runtime.h>
#include <math.h>

static constexpr int NN = 100000;   // nodes
static constexpr int NE = 1600000;  // edges
static constexpr float BN_EPS = 1e-5f;
static constexpr int K_BKT = (NN + 255) / 256;   // 391 coarse buckets (dst>>8)
static constexpr int CH = 4096;                  // edges per partition block

typedef __attribute__((ext_vector_type(8))) short bf16x8;
typedef __attribute__((ext_vector_type(4))) float f32x4;

// bf16 helpers (RNE pack, exact unpack)
__device__ __forceinline__ unsigned short f2bf(float f) {
    unsigned int u = __float_as_uint(f);
    u += 0x7fffu + ((u >> 16) & 1u);
    return (unsigned short)(u >> 16);
}
__device__ __forceinline__ float bf2f(unsigned short b) {
    return __uint_as_float(((unsigned int)b) << 16);
}

// ---------------- coarse bucket histogram (LDS pre-aggregated) ----------------
__global__ __launch_bounds__(256) void bucket_hist(
    const int* __restrict__ dst, int* __restrict__ bhist, int e)
{
    __shared__ int h[K_BKT];
    for (int i = threadIdx.x; i < K_BKT; i += 256) h[i] = 0;
    __syncthreads();
    int stride = gridDim.x * 256;
    for (int i = blockIdx.x * 256 + threadIdx.x; i < e; i += stride)
        atomicAdd(&h[((unsigned)dst[i]) >> 8], 1);
    __syncthreads();
    for (int i = threadIdx.x; i < K_BKT; i += 256)
        if (h[i]) atomicAdd(&bhist[i], h[i]);
}

// ---------------- scan 391 bucket counts -> bases & cursors (1 block) --------
__global__ __launch_bounds__(256) void scan_buckets(
    const int* __restrict__ bhist, int* __restrict__ bbase, int* __restrict__ bcur)
{
    __shared__ int a[512];
    int tid = threadIdx.x;
    a[tid]       = (tid < K_BKT) ? bhist[tid] : 0;
    a[tid + 256] = (tid + 256 < K_BKT) ? bhist[tid + 256] : 0;
    __syncthreads();
    for (int d = 1; d < 512; d <<= 1) {
        int x0 = (tid >= d) ? a[tid - d] : 0;
        int i1 = tid + 256;
        int x1 = (i1 >= d) ? a[i1 - d] : 0;
        __syncthreads();
        a[tid] += x0;
        a[i1]  += x1;
        __syncthreads();
    }
    if (tid < K_BKT) {
        int ex = (tid == 0) ? 0 : a[tid - 1];
        bbase[tid] = ex; bcur[tid] = ex;
    }
    int i1 = tid + 256;
    if (i1 < K_BKT) {
        int ex = a[i1 - 1];
        bbase[i1] = ex; bcur[i1] = ex;
    }
}

// ---------------- partition: bucket-grouped staged writes (coalesced runs) ---
__global__ __launch_bounds__(256) void partition_edges(
    const int* __restrict__ src, const int* __restrict__ dst,
    int* __restrict__ bcur, int* __restrict__ staged, int e)
{
    __shared__ int s_out[CH];       // 16 KB
    __shared__ int cntL[512];       // counts -> inclusive scan
    __shared__ int gbase[K_BKT];
    __shared__ int curL[K_BKT];

    int tid = threadIdx.x;
    int c0 = blockIdx.x * CH;
    int cend = min(c0 + CH, e);

    for (int i = tid; i < 512; i += 256) cntL[i] = 0;
    __syncthreads();

    for (int i = c0 + tid; i < cend; i += 256)
        atomicAdd(&cntL[((unsigned)dst[i]) >> 8], 1);
    __syncthreads();

    for (int b = tid; b < K_BKT; b += 256) {
        int c = cntL[b];
        gbase[b] = (c > 0) ? atomicAdd(&bcur[b], c) : 0;
    }
    __syncthreads();

    for (int d = 1; d < 512; d <<= 1) {
        int x0 = (tid >= d) ? cntL[tid - d] : 0;
        int i1 = tid + 256;
        int x1 = (i1 >= d) ? cntL[i1 - d] : 0;
        __syncthreads();
        cntL[tid] += x0;
        cntL[i1]  += x1;
        __syncthreads();
    }
    for (int b = tid; b < K_BKT; b += 256)
        curL[b] = (b == 0) ? 0 : cntL[b - 1];
    __syncthreads();

    for (int i = c0 + tid; i < cend; i += 256) {
        int s = src[i];
        int d = dst[i];
        int b = ((unsigned)d) >> 8;
        int r = atomicAdd(&curL[b], 1);
        s_out[r] = s | ((d & 255) << 24);
    }
    __syncthreads();

    int wave = tid >> 6, lane = tid & 63;
    for (int b = wave; b < K_BKT; b += 4) {
        int lo = (b == 0) ? 0 : cntL[b - 1];
        int hi = cntL[b];
        int gb = gbase[b];
        for (int i = lo + lane; i < hi; i += 64)
            staged[gb + (i - lo)] = s_out[i];
    }
}

// ---------------- place: per-bucket CSR finalize (XCD-local writes) ----------
__global__ __launch_bounds__(256) void place_edges(
    const int* __restrict__ bbase, const int* __restrict__ staged,
    int* __restrict__ esrc, int* __restrict__ off, int* __restrict__ cnt,
    float* __restrict__ dinv, int n, int e)
{
    __shared__ int cntL[256];
    __shared__ int scn[256];
    __shared__ int curL[256];
    int b = blockIdx.x;
    int tid = threadIdx.x;
    int node0 = b << 8;
    int nN = min(256, n - node0);
    int beg = bbase[b];
    int end = (b == (int)gridDim.x - 1) ? e : bbase[b + 1];

    cntL[tid] = 0;
    __syncthreads();
    for (int i = beg + tid; i < end; i += 256)
        atomicAdd(&cntL[((unsigned)staged[i]) >> 24], 1);
    __syncthreads();
    scn[tid] = cntL[tid];
    __syncthreads();
    for (int d = 1; d < 256; d <<= 1) {
        int x = (tid >= d) ? scn[tid - d] : 0;
        __syncthreads();
        scn[tid] += x;
        __syncthreads();
    }
    int lofs = (tid == 0) ? 0 : scn[tid - 1];
    if (tid < nN) {
        int node = node0 + tid;
        off[node] = beg + lofs;
        cnt[node] = cntL[tid];
        dinv[node] = rsqrtf((float)cntL[tid] + 1.0f);
    }
    curL[tid] = beg + lofs;
    __syncthreads();
    for (int i = beg + tid; i < end; i += 256) {
        int u = staged[i];
        int pos = atomicAdd(&curL[((unsigned)u) >> 24], 1);
        esrc[pos] = u & 0x00FFFFFF;
    }
}

// ---------------- W prep (device body) + fused prep-all kernel ----------------
template<int K, int FOUT>
__device__ __forceinline__ void prep_body(
    const float* __restrict__ W, unsigned short* __restrict__ blob, int t)
{
    constexpr int CT = FOUT / 16;
    int lane = t & 63;
    int ct   = (t >> 6) % CT;
    int ks   = (t >> 6) / CT;
    int col  = ct * 16 + (lane & 15);
    int k0   = ks * 32 + (lane >> 4) * 8;

    union { bf16x8 v; unsigned short e[8]; } u;
#pragma unroll
    for (int j = 0; j < 8; ++j) {
        int kp = k0 + j;
        unsigned short r;
        if (kp < 2 * K) {
            int k = (kp < K) ? kp : kp - K;
            r = f2bf(W[k * FOUT + col]);
        } else {
            float f = W[(kp - 2 * K) * FOUT + col];
            unsigned short h = f2bf(f);
            r = f2bf(f - bf2f(h));
        }
        u.e[j] = r;
    }
    *reinterpret_cast<bf16x8*>(blob + (size_t)t * 8) = u.v;
}

// wt1: 12*4*64=3072, wt2: 6*2*64=768, wt3: 3*1*64=192, bhist zero: K_BKT
__global__ __launch_bounds__(256) void prep_all(
    const float* __restrict__ W1, const float* __restrict__ W2,
    const float* __restrict__ W3, unsigned short* __restrict__ b1,
    unsigned short* __restrict__ b2, unsigned short* __restrict__ b3,
    int* __restrict__ bhist)
{
    int t = blockIdx.x * 256 + threadIdx.x;
    if (t < 3072)            prep_body<128, 64>(W1, b1, t);
    else if (t < 3840)       prep_body<64, 32>(W2, b2, t - 3072);
    else if (t < 4032)       prep_body<32, 16>(W3, b3, t - 3840);
    else if (t < 4032 + K_BKT) bhist[t - 4032] = 0;
}

// ---------------- MFMA GEMM: hw' = (h @ W) * dinv, stored bf16 ----------------
template<int K, int FOUT>
__global__ __launch_bounds__(256) void gemm_mfma(
    const float* __restrict__ h, const unsigned short* __restrict__ wtb,
    const float* __restrict__ dinv, unsigned short* __restrict__ hw, int n)
{
    constexpr int PAD = 8;
    constexpr int LDA = 2 * K + PAD;
    constexpr int CT  = FOUT / 16;
    constexpr int KS  = (3 * K) / 32;
    __shared__ unsigned short As[64 * LDA];

    const int tid  = threadIdx.x;
    const int row0 = blockIdx.x * 64;

    constexpr int QK = K / 4;
    for (int i = tid; i < 64 * QK; i += 256) {
        int r = i / QK;
        int q = i % QK;
        int g = row0 + r;
        float4 v;
        if (g < n) v = *reinterpret_cast<const float4*>(h + (size_t)g * K + q * 4);
        else       v = make_float4(0.f, 0.f, 0.f, 0.f);
        ushort4 hi, lo;
        hi.x = f2bf(v.x); lo.x = f2bf(v.x - bf2f(hi.x));
        hi.y = f2bf(v.y); lo.y = f2bf(v.y - bf2f(hi.y));
        hi.z = f2bf(v.z); lo.z = f2bf(v.z - bf2f(hi.z));
        hi.w = f2bf(v.w); lo.w = f2bf(v.w - bf2f(hi.w));
        *reinterpret_cast<ushort4*>(&As[r * LDA + q * 4])     = hi;
        *reinterpret_cast<ushort4*>(&As[r * LDA + K + q * 4]) = lo;
    }
    __syncthreads();

    const int wave = tid >> 6;
    const int lane = tid & 63;
    const int l15  = lane & 15;
    const int kgrp = (lane >> 4) * 8;
    const int arow = wave * 16 + l15;

    const unsigned short* wlane = wtb + lane * 8;   // + (ks*CT+ct)*512 immediates

    f32x4 acc[CT];
#pragma unroll
    for (int ct = 0; ct < CT; ++ct) acc[ct] = (f32x4){0.f, 0.f, 0.f, 0.f};

#pragma unroll
    for (int ks = 0; ks < KS; ++ks) {
        int kp = ks * 32 + kgrp;
        int ka = (kp >= 2 * K) ? kp - 2 * K : kp;
        bf16x8 a = *reinterpret_cast<const bf16x8*>(&As[arow * LDA + ka]);
#pragma unroll
        for (int ct = 0; ct < CT; ++ct) {
            bf16x8 b = *reinterpret_cast<const bf16x8*>(wlane + (ks * CT + ct) * 512);
            acc[ct] = __builtin_amdgcn_mfma_f32_16x16x32_bf16(a, b, acc[ct], 0, 0, 0);
        }
    }

    const int rbase = wave * 16 + (lane >> 4) * 4;
    float dv[4];
#pragma unroll
    for (int j = 0; j < 4; ++j) {
        int g = row0 + rbase + j;
        dv[j] = (g < n) ? dinv[g] : 0.f;
    }
#pragma unroll
    for (int ct = 0; ct < CT; ++ct) {
#pragma unroll
        for (int j = 0; j < 4; ++j) {
            int g = row0 + rbase + j;
            if (g < n) hw[(size_t)g * FOUT + ct * 16 + l15] = f2bf(acc[ct][j] * dv[j]);
        }
    }
}

// ---------------- gather + self-loop + bias + BN + ReLU (round-7 body) -------
// One node per WAVE. SG = F/4 lanes cover one row; NSG = 64/SG edges per iter.
template<int F>
__global__ __launch_bounds__(256) void gather_bn_relu(
    const int* __restrict__ off, const int* __restrict__ cnt,
    const int* __restrict__ esrc, const float* __restrict__ dinv,
    const unsigned short* __restrict__ hw, const float* __restrict__ bias,
    const float* __restrict__ g, const float* __restrict__ be,
    const float* __restrict__ m, const float* __restrict__ v,
    float* __restrict__ hout, int n)
{
    constexpr int SG  = F / 4;     // lanes covering one row
    constexpr int NSG = 64 / SG;   // edges per iteration
    int node = (blockIdx.x * 256 + threadIdx.x) >> 6;
    if (node >= n) return;
    int lane = threadIdx.x & 63;
    int sg = lane / SG;            // edge slot
    int p  = lane % SG;            // col quad: cols [4p, 4p+3]

    int beg = off[node];
    int num = cnt[node];

    float sx = 0.f, sy = 0.f, sz = 0.f, sw = 0.f;
    int j = sg;
    for (; j + NSG < num; j += 2 * NSG) {
        int s0 = esrc[beg + j];
        int s1 = esrc[beg + j + NSG];
        ushort4 a = *reinterpret_cast<const ushort4*>(hw + (size_t)s0 * F + 4 * p);
        ushort4 b = *reinterpret_cast<const ushort4*>(hw + (size_t)s1 * F + 4 * p);
        sx += bf2f(a.x) + bf2f(b.x);
        sy += bf2f(a.y) + bf2f(b.y);
        sz += bf2f(a.z) + bf2f(b.z);
        sw += bf2f(a.w) + bf2f(b.w);
    }
    if (j < num) {
        int s0 = esrc[beg + j];
        ushort4 a = *reinterpret_cast<const ushort4*>(hw + (size_t)s0 * F + 4 * p);
        sx += bf2f(a.x); sy += bf2f(a.y); sz += bf2f(a.z); sw += bf2f(a.w);
    }
    if (sg == 0) {   // self-loop (hw' = hw*dinv)
        ushort4 a = *reinterpret_cast<const ushort4*>(hw + (size_t)node * F + 4 * p);
        sx += bf2f(a.x); sy += bf2f(a.y); sz += bf2f(a.z); sw += bf2f(a.w);
    }

#pragma unroll
    for (int d = SG; d < 64; d <<= 1) {
        sx += __shfl_xor(sx, d);
        sy += __shfl_xor(sy, d);
        sz += __shfl_xor(sz, d);
        sw += __shfl_xor(sw, d);
    }

    if (sg == 0) {
        int c0 = 4 * p;
        float4 gg = *reinterpret_cast<const float4*>(g + c0);
        float4 vv = *reinterpret_cast<const float4*>(v + c0);
        float4 bb = *reinterpret_cast<const float4*>(bias + c0);
        float4 mm = *reinterpret_cast<const float4*>(m + c0);
        float4 ee = *reinterpret_cast<const float4*>(be + c0);
        float dn = dinv[node];
        float4 y;
        y.x = fmaxf(gg.x * rsqrtf(vv.x + BN_EPS) * (dn * sx + bb.x - mm.x) + ee.x, 0.f);
        y.y = fmaxf(gg.y * rsqrtf(vv.y + BN_EPS) * (dn * sy + bb.y - mm.y) + ee.y, 0.f);
        y.z = fmaxf(gg.z * rsqrtf(vv.z + BN_EPS) * (dn * sz + bb.z - mm.z) + ee.z, 0.f);
        y.w = fmaxf(gg.w * rsqrtf(vv.w + BN_EPS) * (dn * sw + bb.w - mm.w) + ee.w, 0.f);
        *reinterpret_cast<float4*>(hout + (size_t)node * F + c0) = y;
    }
}

// ---------------- layer-3 gather fused with FC(16->8)+sigmoid ----------------
// F=16: SG=4, NSG=16. After reduce, lanes 0..3 hold h3[node][4p..4p+3];
// stage in LDS, lanes 0..7 compute the 16x8 matvec + sigmoid -> out.
__global__ __launch_bounds__(256) void gather_bn_relu_fc(
    const int* __restrict__ off, const int* __restrict__ cnt,
    const int* __restrict__ esrc, const float* __restrict__ dinv,
    const unsigned short* __restrict__ hw, const float* __restrict__ bias,
    const float* __restrict__ g, const float* __restrict__ be,
    const float* __restrict__ m, const float* __restrict__ v,
    const float* __restrict__ fcW, const float* __restrict__ fcb,
    float* __restrict__ out, int n)
{
    constexpr int F = 16, SG = 4, NSG = 16;
    __shared__ float WsF[128];
    __shared__ float bsF[8];
    __shared__ float ybuf[4][16];

    int tid = threadIdx.x;
    if (tid < 128) WsF[tid] = fcW[tid];
    if (tid < 8)   bsF[tid] = fcb[tid];
    __syncthreads();

    int node = (blockIdx.x * 256 + tid) >> 6;
    int wv   = tid >> 6;
    int lane = tid & 63;
    bool act = node < n;

    if (act) {
        int sg = lane / SG;
        int p  = lane % SG;
        int beg = off[node];
        int num = cnt[node];

        float sx = 0.f, sy = 0.f, sz = 0.f, sw = 0.f;
        int j = sg;
        for (; j + NSG < num; j += 2 * NSG) {
            int s0 = esrc[beg + j];
            int s1 = esrc[beg + j + NSG];
            ushort4 a = *reinterpret_cast<const ushort4*>(hw + (size_t)s0 * F + 4 * p);
            ushort4 b = *reinterpret_cast<const ushort4*>(hw + (size_t)s1 * F + 4 * p);
            sx += bf2f(a.x) + bf2f(b.x);
            sy += bf2f(a.y) + bf2f(b.y);
            sz += bf2f(a.z) + bf2f(b.z);
            sw += bf2f(a.w) + bf2f(b.w);
        }
        if (j < num) {
            int s0 = esrc[beg + j];
            ushort4 a = *reinterpret_cast<const ushort4*>(hw + (size_t)s0 * F + 4 * p);
            sx += bf2f(a.x); sy += bf2f(a.y); sz += bf2f(a.z); sw += bf2f(a.w);
        }
        if (sg == 0) {
            ushort4 a = *reinterpret_cast<const ushort4*>(hw + (size_t)node * F + 4 * p);
            sx += bf2f(a.x); sy += bf2f(a.y); sz += bf2f(a.z); sw += bf2f(a.w);
        }

#pragma unroll
        for (int d = SG; d < 64; d <<= 1) {
            sx += __shfl_xor(sx, d);
            sy += __shfl_xor(sy, d);
            sz += __shfl_xor(sz, d);
            sw += __shfl_xor(sw, d);
        }

        if (sg == 0) {
            int c0 = 4 * p;
            float dn = dinv[node];
            float y0 = fmaxf(g[c0+0] * rsqrtf(v[c0+0] + BN_EPS) * (dn * sx + bias[c0+0] - m[c0+0]) + be[c0+0], 0.f);
            float y1 = fmaxf(g[c0+1] * rsqrtf(v[c0+1] + BN_EPS) * (dn * sy + bias[c0+1] - m[c0+1]) + be[c0+1], 0.f);
            float y2 = fmaxf(g[c0+2] * rsqrtf(v[c0+2] + BN_EPS) * (dn * sz + bias[c0+2] - m[c0+2]) + be[c0+2], 0.f);
            float y3 = fmaxf(g[c0+3] * rsqrtf(v[c0+3] + BN_EPS) * (dn * sw + bias[c0+3] - m[c0+3]) + be[c0+3], 0.f);
            ybuf[wv][c0+0] = y0;
            ybuf[wv][c0+1] = y1;
            ybuf[wv][c0+2] = y2;
            ybuf[wv][c0+3] = y3;
        }
    }
    __syncthreads();

    if (act && lane < 8) {
        float o = bsF[lane];
#pragma unroll
        for (int k = 0; k < 16; ++k) o += ybuf[wv][k] * WsF[k * 8 + lane];
        out[(size_t)node * 8 + lane] = 1.0f / (1.0f + expf(-o));
    }
}

// ---------------- launch ----------------
extern "C" void kernel_launch(void* const* d_in, const int* in_sizes, int n_in,
                              void* d_out, int out_size, void* d_ws, size_t ws_size,
                              hipStream_t stream) {
    const float* x   = (const float*)d_in[0];
    const int*   ei  = (const int*)  d_in[1];   // [2, E]: src row then dst row
    const float* W1  = (const float*)d_in[2];
    const float* b1  = (const float*)d_in[3];
    const float* g1  = (const float*)d_in[4];
    const float* be1 = (const float*)d_in[5];
    const float* m1  = (const float*)d_in[6];
    const float* v1  = (const float*)d_in[7];
    const float* W2  = (const float*)d_in[8];
    const float* b2  = (const float*)d_in[9];
    const float* g2  = (const float*)d_in[10];
    const float* be2 = (const float*)d_in[11];
    const float* m2  = (const float*)d_in[12];
    const float* v2  = (const float*)d_in[13];
    const float* W3  = (const float*)d_in[14];
    const float* b3  = (const float*)d_in[15];
    const float* g3  = (const float*)d_in[16];
    const float* be3 = (const float*)d_in[17];
    const float* m3  = (const float*)d_in[18];
    const float* v3  = (const float*)d_in[19];
    const float* fcW = (const float*)d_in[20];
    const float* fcb = (const float*)d_in[21];
    float* out = (float*)d_out;

    const int* src = ei;
    const int* dst = ei + NE;

    char* w = (char*)d_ws;
    float* dinv  = (float*)(w + 0);                 // N f32
    int*   cnt   = (int*)  (w + (512 << 10));       // N i32
    int*   off   = (int*)  (w + (1024 << 10));      // N i32
    int*   bhist = (int*)  (w + (1536 << 10));      // K_BKT i32
    int*   bbase = (int*)  (w + (1600 << 10));      // K_BKT i32
    int*   bcur  = (int*)  (w + (1664 << 10));      // K_BKT i32
    int*   staged= (int*)  (w + (2u << 20));        // E i32 = 6.4 MB
    unsigned short* wt1 = (unsigned short*)(w + (8600u << 10)); // 48 KB blob
    unsigned short* wt2 = wt1 + 24576;                           // 12 KB blob
    unsigned short* wt3 = wt2 + 6144;                            // 3 KB blob
    int*   esrc  = (int*)  (w + (9u << 20));        // E i32 = 6.4 MB
    unsigned short* hw = (unsigned short*)(w + (16u << 20)); // N*64 bf16
    float* H     = (float*)(w + (29u << 20));       // N*64 f32

    float* h1 = H;
    float* h2 = H;

    // ---- W prep blobs + bhist zero (one kernel) ----
    prep_all<<<(4032 + K_BKT + 255) / 256, 256, 0, stream>>>(
        W1, W2, W3, wt1, wt2, wt3, bhist);

    // ---- CSR build ----
    bucket_hist<<<256, 256, 0, stream>>>(dst, bhist, NE);
    scan_buckets<<<1, 256, 0, stream>>>(bhist, bbase, bcur);
    partition_edges<<<(NE + CH - 1) / CH, 256, 0, stream>>>(src, dst, bcur, staged, NE);
    place_edges<<<K_BKT, 256, 0, stream>>>(bbase, staged, esrc, off, cnt, dinv, NN, NE);

    const int GG = (NN * 64 + 255) / 256;   // one wave per node

    // layer 1: 128 -> 64
    gemm_mfma<128, 64><<<(NN + 63) / 64, 256, 0, stream>>>(x, wt1, dinv, hw, NN);
    gather_bn_relu<64><<<GG, 256, 0, stream>>>(
        off, cnt, esrc, dinv, hw, b1, g1, be1, m1, v1, h1, NN);

    // layer 2: 64 -> 32
    gemm_mfma<64, 32><<<(NN + 63) / 64, 256, 0, stream>>>(h1, wt2, dinv, hw, NN);
    gather_bn_relu<32><<<GG, 256, 0, stream>>>(
        off, cnt, esrc, dinv, hw, b2, g2, be2, m2, v2, h2, NN);

    // layer 3: 32 -> 16, fused with FC + sigmoid
    gemm_mfma<32, 16><<<(NN + 63) / 64, 256, 0, stream>>>(h2, wt3, dinv, hw, NN);
    gather_bn_relu_fc<<<GG, 256, 0, stream>>>(
        off, cnt, esrc, dinv, hw, b3, g3, be3, m3, v3, fcW, fcb, out, NN);
}